// Round 4
// baseline (444.909 us; speedup 1.0000x reference)
//
#include <hip/hip_runtime.h>
#include <hip/hip_bf16.h>

#define TT 2048
#define DDIM 1024
#define NHEAD 16
#define HD 64
#define QBLK 64
#define KVBLK 64
#define NQT (TT / QBLK)
#define VST 72

typedef float f32x4 __attribute__((ext_vector_type(4)));
typedef short bf16x8 __attribute__((ext_vector_type(8)));

__device__ __forceinline__ ushort f2bf(float f) {
    __hip_bfloat16 h = __float2bfloat16(f);
    return *reinterpret_cast<ushort*>(&h);
}

__global__ __launch_bounds__(256, 6)
void alibi_attn_kernel(const float* __restrict__ qg,
                       const float* __restrict__ kg,
                       const float* __restrict__ vg,
                       float* __restrict__ out) {
    // single-buffered K (8KB) + V^T (9KB) + per-wave P (8KB) = 25.6KB -> 6 blocks/CU
    __shared__ __align__(16) ushort lds_k[KVBLK * HD];
    __shared__ __align__(16) ushort lds_vt[HD * VST];
    __shared__ __align__(16) ushort lds_p[4][16 * 64];

    const int tid  = threadIdx.x;
    const int wv   = tid >> 6;
    const int lane = tid & 63;
    const int hi   = lane >> 4;   // 0..3
    const int qr   = lane & 15;   // 0..15

    // XCD-locality decode: xcd = flat%8 (dispatch heuristic); each XCD owns 4
    // consecutive bh (K+V = 4MB = one L2), heavy q-tiles first in its stream.
    const int flat = (int)blockIdx.x;          // 0..1023
    const int xcd  = flat & 7;
    const int idx  = flat >> 3;                // 0..127
    const int bh   = xcd * 4 + (idx >> 5);     // 0..31
    const int qt   = NQT - 1 - (idx & 31);     // heavy first
    const int b    = bh >> 4;
    const int h    = bh & 15;
    const int q0   = qt * QBLK;

    const float LOG2E  = 1.4426950408889634f;
    const float slope2 = exp2f(-0.5f * (float)(h + 1)) * LOG2E;
    const float sc2    = 0.125f * LOG2E;

    const size_t bhbase = (size_t)(b * TT) * DDIM + (size_t)(h * HD);

    // ---- Q fragments: wave rows q0 + wv*16 + qr ----
    bf16x8 qf[2];
    {
        const float* gq = qg + bhbase + (size_t)(q0 + wv * 16 + qr) * DDIM + hi * 8;
        #pragma unroll
        for (int ch = 0; ch < 2; ++ch) {
            float4 a0 = *(const float4*)(gq + ch * 32);
            float4 a1 = *(const float4*)(gq + ch * 32 + 4);
            bf16x8 w;
            w[0]=f2bf(a0.x); w[1]=f2bf(a0.y); w[2]=f2bf(a0.z); w[3]=f2bf(a0.w);
            w[4]=f2bf(a1.x); w[5]=f2bf(a1.y); w[6]=f2bf(a1.z); w[7]=f2bf(a1.w);
            qf[ch] = w;
        }
    }

    // staging decomposition (2 slots/thread):
    const int krow = tid >> 3;   // 0..31 (+32 for slot 2)... K rows via slot = tid, tid+256
    const int kcg  = tid & 7;
    const int vdv  = tid & 63;
    const int vkc  = tid >> 6;   // 0..3 (+4 for slot 2)

    float ka[2][8], va[2][8];
    auto issue_loads = [&](int kv0) {
        const float* kp0 = kg + bhbase + (size_t)(kv0 + krow) * DDIM + kcg * 8;
        const float* kp1 = kp0 + (size_t)32 * DDIM;
        *(float4*)&ka[0][0] = *(const float4*)kp0; *(float4*)&ka[0][4] = *(const float4*)(kp0 + 4);
        *(float4*)&ka[1][0] = *(const float4*)kp1; *(float4*)&ka[1][4] = *(const float4*)(kp1 + 4);
        const float* vp0 = vg + bhbase + (size_t)(kv0 + vkc * 8) * DDIM + vdv;
        const float* vp1 = vp0 + (size_t)32 * DDIM;
        #pragma unroll
        for (int jj = 0; jj < 8; ++jj) {
            va[0][jj] = vp0[(size_t)jj * DDIM];
            va[1][jj] = vp1[(size_t)jj * DDIM];
        }
    };
    auto write_stage = [&]() {
        #pragma unroll
        for (int s = 0; s < 2; ++s) {
            bf16x8 w;
            #pragma unroll
            for (int e = 0; e < 8; ++e) w[e] = f2bf(ka[s][e]);
            const int row = krow + s * 32;
            *(bf16x8*)&lds_k[row * 64 + ((kcg ^ (row & 7)) << 3)] = w;
            bf16x8 u;
            #pragma unroll
            for (int e = 0; e < 8; ++e) u[e] = f2bf(va[s][e]);
            const int kc = vkc + s * 4;
            *(bf16x8*)&lds_vt[vdv * VST + ((kc ^ ((vdv >> 3) & 7)) << 3)] = u;
        }
    };

    const int nit = qt + 1;
    issue_loads(q0);            // prologue: diagonal tile first (descending kv)
    write_stage();

    f32x4 oacc[4] = {};
    float mrun = -INFINITY, lrun = 0.f;

    for (int j = 0; j < nit; ++j) {
        const int kv0 = (qt - j) * KVBLK;          // descending
        if (j + 1 < nit) issue_loads(kv0 - KVBLK); // in flight during compute
        __syncthreads();                           // stage writes visible

        const bool diag = (j == 0);

        // ---- S^T = K Q^T: col = q = qr, row(kv16) = hi*4+reg ----
        f32x4 s_acc[4] = {};
        __builtin_amdgcn_s_setprio(1);
        #pragma unroll
        for (int st = 0; st < 4; ++st) {
            if (!diag || st <= wv) {
                const int kvrow = st * 16 + qr;
                #pragma unroll
                for (int ch = 0; ch < 2; ++ch) {
                    bf16x8 kf = *(const bf16x8*)&lds_k[kvrow * 64 + ((((ch << 2) + hi) ^ (kvrow & 7)) << 3)];
                    s_acc[st] = __builtin_amdgcn_mfma_f32_16x16x32_bf16(kf, qf[ch], s_acc[st], 0, 0, 0);
                }
            }
        }
        __builtin_amdgcn_s_setprio(0);

        // ---- in-register online softmax (lane owns q-row qr) ----
        const int ti = q0 + wv * 16 + qr;
        float xv[16];
        float tm = -INFINITY;
        {
            const float relb = (float)(kv0 - ti);
            #pragma unroll
            for (int st = 0; st < 4; ++st)
                #pragma unroll
                for (int r = 0; r < 4; ++r) {
                    const float rel = relb + (float)(st * 16 + hi * 4 + r);
                    float v = s_acc[st][r] * sc2 + rel * slope2;
                    if (diag) v = (rel <= 0.f) ? v : -INFINITY;
                    xv[st * 4 + r] = v;
                    tm = fmaxf(tm, v);
                }
        }
        tm = fmaxf(tm, __shfl_xor(tm, 16));
        tm = fmaxf(tm, __shfl_xor(tm, 32));
        if (!__all(tm <= mrun + 8.f)) {   // defer-max: rare after the diagonal tile
            const float mnew = fmaxf(mrun, tm);
            const float fsc  = exp2f(mrun - mnew);
            mrun = mnew;
            lrun *= fsc;
            float fo[4];
            #pragma unroll
            for (int r = 0; r < 4; ++r) fo[r] = __shfl(fsc, hi * 4 + r);
            #pragma unroll
            for (int dt = 0; dt < 4; ++dt)
                #pragma unroll
                for (int r = 0; r < 4; ++r) oacc[dt][r] *= fo[r];
        }
        float psum = 0.f;
        #pragma unroll
        for (int i = 0; i < 16; ++i) { xv[i] = exp2f(xv[i] - mrun); psum += xv[i]; }
        lrun += psum;

        // ---- P^T -> P in LDS (stride 64 + XOR swizzle; per-wave, no barrier) ----
        #pragma unroll
        for (int st = 0; st < 4; ++st) {
            ushort4 w;
            w.x = f2bf(xv[st * 4 + 0]); w.y = f2bf(xv[st * 4 + 1]);
            w.z = f2bf(xv[st * 4 + 2]); w.w = f2bf(xv[st * 4 + 3]);
            const int slot8 = (st << 1) | (hi >> 1);
            *(ushort4*)&lds_p[wv][qr * 64 + ((slot8 ^ (qr & 7)) << 3) + ((hi & 1) << 2)] = w;
        }

        // ---- O += P V ----
        __builtin_amdgcn_s_setprio(1);
        #pragma unroll
        for (int ks = 0; ks < 2; ++ks) {
            if (!diag || wv >= 2 || ks == 0) {
                bf16x8 pa = *(const bf16x8*)&lds_p[wv][qr * 64 + ((((ks << 2) | hi) ^ (qr & 7)) << 3)];
                #pragma unroll
                for (int dt = 0; dt < 4; ++dt) {
                    const int dv = dt * 16 + qr;
                    bf16x8 vb = *(const bf16x8*)&lds_vt[dv * VST + ((((ks << 2) + hi) ^ ((dv >> 3) & 7)) << 3)];
                    oacc[dt] = __builtin_amdgcn_mfma_f32_16x16x32_bf16(pa, vb, oacc[dt], 0, 0, 0);
                }
            }
        }
        __builtin_amdgcn_s_setprio(0);

        if (j + 1 < nit) {
            __syncthreads();   // all waves done reading K/V
            write_stage();     // next tile into the (single) buffer
        }
    }

    // ---- epilogue ----
    {
        float lr = lrun;
        lr += __shfl_xor(lr, 16);
        lr += __shfl_xor(lr, 32);
        const float linv = 1.0f / lr;
        #pragma unroll
        for (int r = 0; r < 4; ++r) {
            const float inv = __shfl(linv, hi * 4 + r);
            float* go = out + bhbase + (size_t)(q0 + wv * 16 + hi * 4 + r) * DDIM;
            #pragma unroll
            for (int dt = 0; dt < 4; ++dt)
                go[dt * 16 + qr] = oacc[dt][r] * inv;
        }
    }
}

extern "C" void kernel_launch(void* const* d_in, const int* in_sizes, int n_in,
                              void* d_out, int out_size, void* d_ws, size_t ws_size,
                              hipStream_t stream) {
    (void)in_sizes; (void)n_in; (void)d_ws; (void)ws_size; (void)out_size;
    const float* q = (const float*)d_in[0];
    const float* k = (const float*)d_in[1];
    const float* v = (const float*)d_in[2];
    float* o = (float*)d_out;
    alibi_attn_kernel<<<dim3(NQT * 2 * NHEAD), 256, 0, stream>>>(q, k, v, o);
}

// Round 5
// 119.043 us; speedup vs baseline: 3.7374x; 3.7374x over previous
//
#include <hip/hip_runtime.h>
#include <hip/hip_bf16.h>

#define TT 2048
#define DDIM 1024
#define NHEAD 16
#define HD 64
#define QBLK 64
#define KVBLK 64
#define NQT (TT / QBLK)
#define VST 72

typedef float f32x4 __attribute__((ext_vector_type(4)));
typedef short bf16x8 __attribute__((ext_vector_type(8)));

__device__ __forceinline__ ushort f2bf(float f) {
    __hip_bfloat16 h = __float2bfloat16(f);
    return *reinterpret_cast<ushort*>(&h);
}

// (256,4): VGPR cap 128 — kernel naturally uses ~80 (R3), so NO spills.
// (256,6) in R4 forced VGPR=40 -> 580MB scratch spill traffic, 5x regression.
__global__ __launch_bounds__(256, 4)
void alibi_attn_kernel(const float* __restrict__ qg,
                       const float* __restrict__ kg,
                       const float* __restrict__ vg,
                       float* __restrict__ out) {
    // single-buffered K (8KB) + V^T (9KB) + per-wave P (8KB) = 25.6KB -> LDS allows 6 blocks/CU
    __shared__ __align__(16) ushort lds_k[KVBLK * HD];
    __shared__ __align__(16) ushort lds_vt[HD * VST];
    __shared__ __align__(16) ushort lds_p[4][16 * 64];

    const int tid  = threadIdx.x;
    const int wv   = tid >> 6;
    const int lane = tid & 63;
    const int hi   = lane >> 4;   // 0..3
    const int qr   = lane & 15;   // 0..15

    // XCD-locality decode: xcd = flat%8 (round-robin dispatch heuristic); each XCD
    // owns 4 consecutive bh (K+V = 4MB = one L2), heavy q-tiles first in its stream.
    const int flat = (int)blockIdx.x;          // 0..1023
    const int xcd  = flat & 7;
    const int idx  = flat >> 3;                // 0..127
    const int bh   = xcd * 4 + (idx >> 5);     // 0..31
    const int qt   = NQT - 1 - (idx & 31);     // heavy first
    const int b    = bh >> 4;
    const int h    = bh & 15;
    const int q0   = qt * QBLK;

    const float LOG2E  = 1.4426950408889634f;
    const float slope2 = exp2f(-0.5f * (float)(h + 1)) * LOG2E;
    const float sc2    = 0.125f * LOG2E;

    const size_t bhbase = (size_t)(b * TT) * DDIM + (size_t)(h * HD);

    // ---- Q fragments: wave rows q0 + wv*16 + qr ----
    bf16x8 qf[2];
    {
        const float* gq = qg + bhbase + (size_t)(q0 + wv * 16 + qr) * DDIM + hi * 8;
        #pragma unroll
        for (int ch = 0; ch < 2; ++ch) {
            float4 a0 = *(const float4*)(gq + ch * 32);
            float4 a1 = *(const float4*)(gq + ch * 32 + 4);
            bf16x8 w;
            w[0]=f2bf(a0.x); w[1]=f2bf(a0.y); w[2]=f2bf(a0.z); w[3]=f2bf(a0.w);
            w[4]=f2bf(a1.x); w[5]=f2bf(a1.y); w[6]=f2bf(a1.z); w[7]=f2bf(a1.w);
            qf[ch] = w;
        }
    }

    // staging decomposition (2 slots/thread):
    const int krow = tid >> 3;   // 0..31 (+32 for slot 2)
    const int kcg  = tid & 7;
    const int vdv  = tid & 63;
    const int vkc  = tid >> 6;   // 0..3 (+4 for slot 2)

    float ka[2][8], va[2][8];
    auto issue_loads = [&](int kv0) {
        const float* kp0 = kg + bhbase + (size_t)(kv0 + krow) * DDIM + kcg * 8;
        const float* kp1 = kp0 + (size_t)32 * DDIM;
        *(float4*)&ka[0][0] = *(const float4*)kp0; *(float4*)&ka[0][4] = *(const float4*)(kp0 + 4);
        *(float4*)&ka[1][0] = *(const float4*)kp1; *(float4*)&ka[1][4] = *(const float4*)(kp1 + 4);
        const float* vp0 = vg + bhbase + (size_t)(kv0 + vkc * 8) * DDIM + vdv;
        const float* vp1 = vp0 + (size_t)32 * DDIM;
        #pragma unroll
        for (int jj = 0; jj < 8; ++jj) {
            va[0][jj] = vp0[(size_t)jj * DDIM];
            va[1][jj] = vp1[(size_t)jj * DDIM];
        }
    };
    auto write_stage = [&]() {
        #pragma unroll
        for (int s = 0; s < 2; ++s) {
            bf16x8 w;
            #pragma unroll
            for (int e = 0; e < 8; ++e) w[e] = f2bf(ka[s][e]);
            const int row = krow + s * 32;
            *(bf16x8*)&lds_k[row * 64 + ((kcg ^ (row & 7)) << 3)] = w;
            bf16x8 u;
            #pragma unroll
            for (int e = 0; e < 8; ++e) u[e] = f2bf(va[s][e]);
            const int kc = vkc + s * 4;
            *(bf16x8*)&lds_vt[vdv * VST + ((kc ^ ((vdv >> 3) & 7)) << 3)] = u;
        }
    };

    const int nit = qt + 1;
    issue_loads(q0);            // prologue: diagonal tile first (descending kv)
    write_stage();

    f32x4 oacc[4] = {};
    float mrun = -INFINITY, lrun = 0.f;

    for (int j = 0; j < nit; ++j) {
        const int kv0 = (qt - j) * KVBLK;          // descending
        if (j + 1 < nit) issue_loads(kv0 - KVBLK); // in flight during compute
        __syncthreads();                           // stage writes visible

        const bool diag = (j == 0);

        // ---- S^T = K Q^T: col = q = qr, row(kv16) = hi*4+reg ----
        f32x4 s_acc[4] = {};
        __builtin_amdgcn_s_setprio(1);
        #pragma unroll
        for (int st = 0; st < 4; ++st) {
            if (!diag || st <= wv) {
                const int kvrow = st * 16 + qr;
                #pragma unroll
                for (int ch = 0; ch < 2; ++ch) {
                    bf16x8 kf = *(const bf16x8*)&lds_k[kvrow * 64 + ((((ch << 2) + hi) ^ (kvrow & 7)) << 3)];
                    s_acc[st] = __builtin_amdgcn_mfma_f32_16x16x32_bf16(kf, qf[ch], s_acc[st], 0, 0, 0);
                }
            }
        }
        __builtin_amdgcn_s_setprio(0);

        // ---- in-register online softmax (lane owns q-row qr) ----
        const int ti = q0 + wv * 16 + qr;
        float xv[16];
        float tm = -INFINITY;
        {
            const float relb = (float)(kv0 - ti);
            #pragma unroll
            for (int st = 0; st < 4; ++st)
                #pragma unroll
                for (int r = 0; r < 4; ++r) {
                    const float rel = relb + (float)(st * 16 + hi * 4 + r);
                    float v = s_acc[st][r] * sc2 + rel * slope2;
                    if (diag) v = (rel <= 0.f) ? v : -INFINITY;
                    xv[st * 4 + r] = v;
                    tm = fmaxf(tm, v);
                }
        }
        tm = fmaxf(tm, __shfl_xor(tm, 16));
        tm = fmaxf(tm, __shfl_xor(tm, 32));
        if (!__all(tm <= mrun + 8.f)) {   // defer-max: rare after the diagonal tile
            const float mnew = fmaxf(mrun, tm);
            const float fsc  = exp2f(mrun - mnew);
            mrun = mnew;
            lrun *= fsc;
            float fo[4];
            #pragma unroll
            for (int r = 0; r < 4; ++r) fo[r] = __shfl(fsc, hi * 4 + r);
            #pragma unroll
            for (int dt = 0; dt < 4; ++dt)
                #pragma unroll
                for (int r = 0; r < 4; ++r) oacc[dt][r] *= fo[r];
        }
        float psum = 0.f;
        #pragma unroll
        for (int i = 0; i < 16; ++i) { xv[i] = exp2f(xv[i] - mrun); psum += xv[i]; }
        lrun += psum;

        // ---- P^T -> P in LDS (stride 64 + XOR swizzle; per-wave, no barrier) ----
        #pragma unroll
        for (int st = 0; st < 4; ++st) {
            ushort4 w;
            w.x = f2bf(xv[st * 4 + 0]); w.y = f2bf(xv[st * 4 + 1]);
            w.z = f2bf(xv[st * 4 + 2]); w.w = f2bf(xv[st * 4 + 3]);
            const int slot8 = (st << 1) | (hi >> 1);
            *(ushort4*)&lds_p[wv][qr * 64 + ((slot8 ^ (qr & 7)) << 3) + ((hi & 1) << 2)] = w;
        }

        // ---- O += P V ----
        __builtin_amdgcn_s_setprio(1);
        #pragma unroll
        for (int ks = 0; ks < 2; ++ks) {
            if (!diag || wv >= 2 || ks == 0) {
                bf16x8 pa = *(const bf16x8*)&lds_p[wv][qr * 64 + ((((ks << 2) | hi) ^ (qr & 7)) << 3)];
                #pragma unroll
                for (int dt = 0; dt < 4; ++dt) {
                    const int dv = dt * 16 + qr;
                    bf16x8 vb = *(const bf16x8*)&lds_vt[dv * VST + ((((ks << 2) + hi) ^ ((dv >> 3) & 7)) << 3)];
                    oacc[dt] = __builtin_amdgcn_mfma_f32_16x16x32_bf16(pa, vb, oacc[dt], 0, 0, 0);
                }
            }
        }
        __builtin_amdgcn_s_setprio(0);

        if (j + 1 < nit) {
            __syncthreads();   // all waves done reading K/V
            write_stage();     // next tile into the (single) buffer
        }
    }

    // ---- epilogue ----
    {
        float lr = lrun;
        lr += __shfl_xor(lr, 16);
        lr += __shfl_xor(lr, 32);
        const float linv = 1.0f / lr;
        #pragma unroll
        for (int r = 0; r < 4; ++r) {
            const float inv = __shfl(linv, hi * 4 + r);
            float* go = out + bhbase + (size_t)(q0 + wv * 16 + hi * 4 + r) * DDIM;
            #pragma unroll
            for (int dt = 0; dt < 4; ++dt)
                go[dt * 16 + qr] = oacc[dt][r] * inv;
        }
    }
}

extern "C" void kernel_launch(void* const* d_in, const int* in_sizes, int n_in,
                              void* d_out, int out_size, void* d_ws, size_t ws_size,
                              hipStream_t stream) {
    (void)in_sizes; (void)n_in; (void)d_ws; (void)ws_size; (void)out_size;
    const float* q = (const float*)d_in[0];
    const float* k = (const float*)d_in[1];
    const float* v = (const float*)d_in[2];
    float* o = (float*)d_out;
    alibi_attn_kernel<<<dim3(NQT * 2 * NHEAD), 256, 0, stream>>>(q, k, v, o);
}

// Round 6
// 76.519 us; speedup vs baseline: 5.8144x; 1.5557x over previous
//
#include <hip/hip_runtime.h>
#include <hip/hip_bf16.h>

#define TT 2048
#define DDIM 1024
#define NHEAD 16
#define HD 64
#define QBLK 64
#define KVBLK 64
#define NQT (TT / QBLK)
#define VST 72

typedef float f32x4 __attribute__((ext_vector_type(4)));
typedef short bf16x8 __attribute__((ext_vector_type(8)));

__device__ __forceinline__ ushort f2bf(float f) {
    __hip_bfloat16 h = __float2bfloat16(f);
    return *reinterpret_cast<ushort*>(&h);
}

// (256,2): VGPR cap 256 — kernel naturally uses ~80 (R3-proven), NO spills.
// (256,6)->40 VGPR and (256,4)->64 VGPR both spilled (50-580MB scratch traffic).
__global__ __launch_bounds__(256, 2)
void alibi_attn_kernel(const float* __restrict__ qg,
                       const float* __restrict__ kg,
                       const float* __restrict__ vg,
                       float* __restrict__ out) {
    // single-buffered K (8KB) + V^T (9KB) + per-wave P (8KB) = 25.6KB -> LDS allows 6 blocks/CU
    __shared__ __align__(16) ushort lds_k[KVBLK * HD];
    __shared__ __align__(16) ushort lds_vt[HD * VST];
    __shared__ __align__(16) ushort lds_p[4][16 * 64];

    const int tid  = threadIdx.x;
    const int wv   = tid >> 6;
    const int lane = tid & 63;
    const int hi   = lane >> 4;   // 0..3
    const int qr   = lane & 15;   // 0..15

    // XCD-locality decode: xcd = flat%8 (round-robin dispatch heuristic); each XCD
    // owns 4 consecutive bh (K+V = 4MB = one L2), heavy q-tiles first in its stream.
    // Confirmed R5: FETCH 195MB -> 87MB.
    const int flat = (int)blockIdx.x;          // 0..1023
    const int xcd  = flat & 7;
    const int idx  = flat >> 3;                // 0..127
    const int bh   = xcd * 4 + (idx >> 5);     // 0..31
    const int qt   = NQT - 1 - (idx & 31);     // heavy first
    const int b    = bh >> 4;
    const int h    = bh & 15;
    const int q0   = qt * QBLK;

    const float LOG2E  = 1.4426950408889634f;
    const float slope2 = exp2f(-0.5f * (float)(h + 1)) * LOG2E;
    const float sc2    = 0.125f * LOG2E;

    const size_t bhbase = (size_t)(b * TT) * DDIM + (size_t)(h * HD);

    // ---- Q fragments: wave rows q0 + wv*16 + qr ----
    bf16x8 qf[2];
    {
        const float* gq = qg + bhbase + (size_t)(q0 + wv * 16 + qr) * DDIM + hi * 8;
        #pragma unroll
        for (int ch = 0; ch < 2; ++ch) {
            float4 a0 = *(const float4*)(gq + ch * 32);
            float4 a1 = *(const float4*)(gq + ch * 32 + 4);
            bf16x8 w;
            w[0]=f2bf(a0.x); w[1]=f2bf(a0.y); w[2]=f2bf(a0.z); w[3]=f2bf(a0.w);
            w[4]=f2bf(a1.x); w[5]=f2bf(a1.y); w[6]=f2bf(a1.z); w[7]=f2bf(a1.w);
            qf[ch] = w;
        }
    }

    // staging decomposition (2 slots/thread):
    const int krow = tid >> 3;   // 0..31 (+32 for slot 2)
    const int kcg  = tid & 7;
    const int vdv  = tid & 63;
    const int vkc  = tid >> 6;   // 0..3 (+4 for slot 2)

    float ka[2][8], va[2][8];
    auto issue_loads = [&](int kv0) {
        const float* kp0 = kg + bhbase + (size_t)(kv0 + krow) * DDIM + kcg * 8;
        const float* kp1 = kp0 + (size_t)32 * DDIM;
        *(float4*)&ka[0][0] = *(const float4*)kp0; *(float4*)&ka[0][4] = *(const float4*)(kp0 + 4);
        *(float4*)&ka[1][0] = *(const float4*)kp1; *(float4*)&ka[1][4] = *(const float4*)(kp1 + 4);
        const float* vp0 = vg + bhbase + (size_t)(kv0 + vkc * 8) * DDIM + vdv;
        const float* vp1 = vp0 + (size_t)32 * DDIM;
        #pragma unroll
        for (int jj = 0; jj < 8; ++jj) {
            va[0][jj] = vp0[(size_t)jj * DDIM];
            va[1][jj] = vp1[(size_t)jj * DDIM];
        }
    };
    auto write_stage = [&]() {
        #pragma unroll
        for (int s = 0; s < 2; ++s) {
            bf16x8 w;
            #pragma unroll
            for (int e = 0; e < 8; ++e) w[e] = f2bf(ka[s][e]);
            const int row = krow + s * 32;
            *(bf16x8*)&lds_k[row * 64 + ((kcg ^ (row & 7)) << 3)] = w;
            bf16x8 u;
            #pragma unroll
            for (int e = 0; e < 8; ++e) u[e] = f2bf(va[s][e]);
            const int kc = vkc + s * 4;
            *(bf16x8*)&lds_vt[vdv * VST + ((kc ^ ((vdv >> 3) & 7)) << 3)] = u;
        }
    };

    const int nit = qt + 1;
    issue_loads(q0);            // prologue: diagonal tile first (descending kv)
    write_stage();

    f32x4 oacc[4] = {};
    float mrun = -INFINITY, lrun = 0.f;

    for (int j = 0; j < nit; ++j) {
        const int kv0 = (qt - j) * KVBLK;          // descending
        if (j + 1 < nit) issue_loads(kv0 - KVBLK); // in flight during compute
        __syncthreads();                           // stage writes visible

        const bool diag = (j == 0);

        // ---- S^T = K Q^T: col = q = qr, row(kv16) = hi*4+reg ----
        f32x4 s_acc[4] = {};
        __builtin_amdgcn_s_setprio(1);
        #pragma unroll
        for (int st = 0; st < 4; ++st) {
            if (!diag || st <= wv) {
                const int kvrow = st * 16 + qr;
                #pragma unroll
                for (int ch = 0; ch < 2; ++ch) {
                    bf16x8 kf = *(const bf16x8*)&lds_k[kvrow * 64 + ((((ch << 2) + hi) ^ (kvrow & 7)) << 3)];
                    s_acc[st] = __builtin_amdgcn_mfma_f32_16x16x32_bf16(kf, qf[ch], s_acc[st], 0, 0, 0);
                }
            }
        }
        __builtin_amdgcn_s_setprio(0);

        // ---- in-register online softmax (lane owns q-row qr) ----
        const int ti = q0 + wv * 16 + qr;
        float xv[16];
        float tm = -INFINITY;
        {
            const float relb = (float)(kv0 - ti);
            #pragma unroll
            for (int st = 0; st < 4; ++st)
                #pragma unroll
                for (int r = 0; r < 4; ++r) {
                    const float rel = relb + (float)(st * 16 + hi * 4 + r);
                    float v = s_acc[st][r] * sc2 + rel * slope2;
                    if (diag) v = (rel <= 0.f) ? v : -INFINITY;
                    xv[st * 4 + r] = v;
                    tm = fmaxf(tm, v);
                }
        }
        tm = fmaxf(tm, __shfl_xor(tm, 16));
        tm = fmaxf(tm, __shfl_xor(tm, 32));
        if (!__all(tm <= mrun + 8.f)) {   // defer-max: rare after the diagonal tile
            const float mnew = fmaxf(mrun, tm);
            const float fsc  = exp2f(mrun - mnew);
            mrun = mnew;
            lrun *= fsc;
            float fo[4];
            #pragma unroll
            for (int r = 0; r < 4; ++r) fo[r] = __shfl(fsc, hi * 4 + r);
            #pragma unroll
            for (int dt = 0; dt < 4; ++dt)
                #pragma unroll
                for (int r = 0; r < 4; ++r) oacc[dt][r] *= fo[r];
        }
        float psum = 0.f;
        #pragma unroll
        for (int i = 0; i < 16; ++i) { xv[i] = exp2f(xv[i] - mrun); psum += xv[i]; }
        lrun += psum;

        // ---- P^T -> P in LDS (stride 64 + XOR swizzle; per-wave, no barrier) ----
        #pragma unroll
        for (int st = 0; st < 4; ++st) {
            ushort4 w;
            w.x = f2bf(xv[st * 4 + 0]); w.y = f2bf(xv[st * 4 + 1]);
            w.z = f2bf(xv[st * 4 + 2]); w.w = f2bf(xv[st * 4 + 3]);
            const int slot8 = (st << 1) | (hi >> 1);
            *(ushort4*)&lds_p[wv][qr * 64 + ((slot8 ^ (qr & 7)) << 3) + ((hi & 1) << 2)] = w;
        }

        // ---- O += P V ----
        __builtin_amdgcn_s_setprio(1);
        #pragma unroll
        for (int ks = 0; ks < 2; ++ks) {
            if (!diag || wv >= 2 || ks == 0) {
                bf16x8 pa = *(const bf16x8*)&lds_p[wv][qr * 64 + ((((ks << 2) | hi) ^ (qr & 7)) << 3)];
                #pragma unroll
                for (int dt = 0; dt < 4; ++dt) {
                    const int dv = dt * 16 + qr;
                    bf16x8 vb = *(const bf16x8*)&lds_vt[dv * VST + ((((ks << 2) + hi) ^ ((dv >> 3) & 7)) << 3)];
                    oacc[dt] = __builtin_amdgcn_mfma_f32_16x16x32_bf16(pa, vb, oacc[dt], 0, 0, 0);
                }
            }
        }
        __builtin_amdgcn_s_setprio(0);

        if (j + 1 < nit) {
            __syncthreads();   // all waves done reading K/V
            write_stage();     // next tile into the (single) buffer
        }
    }

    // ---- epilogue ----
    {
        float lr = lrun;
        lr += __shfl_xor(lr, 16);
        lr += __shfl_xor(lr, 32);
        const float linv = 1.0f / lr;
        #pragma unroll
        for (int r = 0; r < 4; ++r) {
            const float inv = __shfl(linv, hi * 4 + r);
            float* go = out + bhbase + (size_t)(q0 + wv * 16 + hi * 4 + r) * DDIM;
            #pragma unroll
            for (int dt = 0; dt < 4; ++dt)
                go[dt * 16 + qr] = oacc[dt][r] * inv;
        }
    }
}

extern "C" void kernel_launch(void* const* d_in, const int* in_sizes, int n_in,
                              void* d_out, int out_size, void* d_ws, size_t ws_size,
                              hipStream_t stream) {
    (void)in_sizes; (void)n_in; (void)d_ws; (void)ws_size; (void)out_size;
    const float* q = (const float*)d_in[0];
    const float* k = (const float*)d_in[1];
    const float* v = (const float*)d_in[2];
    float* o = (float*)d_out;
    alibi_attn_kernel<<<dim3(NQT * 2 * NHEAD), 256, 0, stream>>>(q, k, v, o);
}